// Round 6
// baseline (753.296 us; speedup 1.0000x reference)
//
#include <hip/hip_runtime.h>
#include <hip/hip_fp16.h>
#include <cstdint>

#define DI __device__ __forceinline__

typedef _Float16 f16;
typedef _Float16 half8 __attribute__((ext_vector_type(8)));
typedef float f32x4 __attribute__((ext_vector_type(4)));

constexpr int NF  = 4096;   // features (in = out)
constexpr int TSZ = 512;    // crossbar tile size

// Match JAX f32 weak-typing: f64 python scalars cast to f32 at op time.
constexpr float G_MIN  = (float)(1.0 / 1.0e6);
constexpr float GRANGE = (float)(1.0e-4 - 1.0e-6);            // G_MAX - G_MIN
constexpr float QSTEP  = (float)((1.0e-4 - 1.0e-6) / 15.0);   // (G_MAX-G_MIN)/(2^4-1)

// ---------------- K0: prep = convert_x (blocks 0..4095) ∥ minmax partials ----
__global__ __launch_bounds__(256)
void prep(const float* __restrict__ x, f16* __restrict__ xh,
          const float* __restrict__ w,
          float* __restrict__ pmin, float* __restrict__ pmax) {
    int bid = blockIdx.x;
    int t = threadIdx.x;
    if (bid < 4096) {
        int idx = bid * 256 + t;              // 1M float4
        float4 v = ((const float4*)x)[idx];
        union { f16 h[4]; uint2 u; } o;
        o.h[0] = (f16)v.x; o.h[1] = (f16)v.y; o.h[2] = (f16)v.z; o.h[3] = (f16)v.w;
        ((uint2*)xh)[idx] = o.u;
        return;
    }
    int b2 = bid - 4096;                      // 0..1023
    int tile = b2 >> 4, sub = b2 & 15;
    int it = tile >> 3, jt = tile & 7;
    const float* base = w + (size_t)(it * TSZ + sub * 32) * NF + jt * TSZ;
    float mn = 3.4e38f, mx = -3.4e38f;
#pragma unroll
    for (int i = 0; i < 16; ++i) {
        int idx = i * 256 + t;                // 32 rows x 128 float4
        int r = idx >> 7, c4 = idx & 127;
        float4 v = ((const float4*)(base + (size_t)r * NF))[c4];
        mn = fminf(mn, fminf(fminf(v.x, v.y), fminf(v.z, v.w)));
        mx = fmaxf(mx, fmaxf(fmaxf(v.x, v.y), fmaxf(v.z, v.w)));
    }
    for (int d = 1; d < 64; d <<= 1) {
        mn = fminf(mn, __shfl_xor(mn, d)); mx = fmaxf(mx, __shfl_xor(mx, d));
    }
    __shared__ float smn[4], smx[4];
    int wv = t >> 6;
    if ((t & 63) == 0) { smn[wv] = mn; smx[wv] = mx; }
    __syncthreads();
    if (t == 0) {
        pmin[b2] = fminf(fminf(smn[0], smn[1]), fminf(smn[2], smn[3]));
        pmax[b2] = fmaxf(fmaxf(smx[0], smx[1]), fmaxf(smx[2], smx[3]));
    }
}

// -------- K2: transform w -> wq_f16, H_f16 (transposed: [tile][n][k]) --------
// Quantization arithmetic must match jnp bit-for-bit: unfused f32 mul/add, IEEE
// f32 divide, rintf (ties-to-even). fp contract OFF for this kernel.
__global__ void transform_w(const float* __restrict__ w,
                            const float* __restrict__ pmin, const float* __restrict__ pmax,
                            f16* __restrict__ wq_t, f16* __restrict__ h_t) {
#pragma clang fp contract(off)
    __shared__ f16 lwq[64][72];
    __shared__ f16 lh[64][72];
    int tile = blockIdx.x >> 6; int it = tile >> 3, jt = tile & 7;
    int sub = blockIdx.x & 63; int k0 = (sub >> 3) << 6, n0 = (sub & 7) << 6;
    float wmin = 3.4e38f, wmax = -3.4e38f;
#pragma unroll
    for (int u = 0; u < 16; ++u) {
        wmin = fminf(wmin, pmin[tile * 16 + u]);
        wmax = fmaxf(wmax, pmax[tile * 16 + u]);
    }
    float s = GRANGE / (wmax - wmin + 1e-12f);
    float inv_s = 1.0f / s;
    int t = threadIdx.x, cn = t & 63, r0 = t >> 6;
    for (int rr = 0; rr < 16; ++rr) {
        int rk = rr * 4 + r0;     // local k in [0,64)
        float wv = w[(size_t)(it * TSZ + k0 + rk) * NF + jt * TSZ + n0 + cn];
        float cond  = (wv - wmin) * s + G_MIN;            // unfused, = reference
        float q     = rintf((cond - G_MIN) / QSTEP);      // ties-to-even, IEEE div
        float condq = q * QSTEP + G_MIN;                  // unfused, = reference
        float wqv   = (condq - G_MIN) * inv_s + wmin;     // our own math (any rounding)
        float rw    = 2.0f * ((512.0f - (float)(k0 + rk)) + ((float)(n0 + cn) + 1.0f));
        float ge    = 1.0f / (1.0f / condq + rw);         // IEEE f32 divs, = reference
        lwq[rk][cn] = (f16)wqv;
        lh[rk][cn]  = (f16)(ge * inv_s);
    }
    __syncthreads();
    for (int pp = 0; pp < 8; ++pp) {
        int nl = pp * 8 + (t >> 5);
        int kp = (t & 31) * 2;
        union { f16 h[2]; uint32_t u; } a, b;
        a.h[0] = lwq[kp][nl]; a.h[1] = lwq[kp + 1][nl];
        b.h[0] = lh[kp][nl];  b.h[1] = lh[kp + 1][nl];
        size_t obase = (size_t)tile * TSZ * TSZ + (size_t)(n0 + nl) * TSZ + k0 + kp;
        *(uint32_t*)(wq_t + obase) = a.u;
        *(uint32_t*)(h_t + obase)  = b.u;
    }
}

// ---------------- fused GEMM: 512 thr, 8 waves (4m x 2n), tile M=256 N=128 ----
//   P = x_tile @ wq^T  (stats only)   and   Q = x_tile @ h^T (stats + store)
DI void gl16(const void* g, void* l) {
    auto gp = reinterpret_cast<const uint32_t __attribute__((address_space(1)))*>(
        reinterpret_cast<uintptr_t>(g));
    auto lp = reinterpret_cast<uint32_t __attribute__((address_space(3)))*>(
        reinterpret_cast<uintptr_t>(l));
    __builtin_amdgcn_global_load_lds(gp, lp, 16, 0, 0);
}

__global__ __launch_bounds__(512, 4)
void gemm_fused(const f16* __restrict__ A, const f16* __restrict__ B1,
                const f16* __restrict__ B2, f16* __restrict__ Qout,
                float* __restrict__ pmx, float* __restrict__ pmn, float* __restrict__ psm,
                float* __restrict__ qmx, float* __restrict__ qmn, float* __restrict__ qsm) {
    // 64 KB total: As 2x16KB | B1s 2x8KB | B2s 2x8KB; sred aliases As after loop
    __shared__ __align__(16) char smem[65536];
    f16* As  = (f16*)smem;               // [2][256r * 32k]
    f16* B1s = (f16*)(smem + 32768);     // [2][128r * 32k]
    f16* B2s = (f16*)(smem + 49152);     // [2][128r * 32k]
    float* sred = (float*)smem;          // [256][2][3] (aliases As; used after loop)

    int bx = blockIdx.x;                 // 64 tiles * 4 mb * 4 nb = 1024 blocks
    int tile = bx >> 4, mb = (bx >> 2) & 3, nb = bx & 3;
    int it = tile >> 3;
    int t = threadIdx.x, lane = t & 63, w = t >> 6;   // 8 waves
    int wr = w >> 1, wc = w & 1;                      // 4 m-waves x 2 n-waves

    const f16* Ab  = A  + (size_t)(mb * 256) * NF + it * TSZ;
    const f16* B1b = B1 + ((size_t)tile * TSZ + nb * 128) * TSZ;
    const f16* B2b = B2 + ((size_t)tile * TSZ + nb * 128) * TSZ;

    // staging: A 1024 chunks (t, t+512), B1/B2 512 chunks (t) per K-step.
    // chunk l -> LDS halfs [8l, 8l+8); source k pre-swizzled: (slot^((row>>1)&3))*8
    int la1 = t, la2 = t + 512;
    int ra1 = la1 >> 2, ka1 = ((la1 & 3) ^ ((ra1 >> 1) & 3)) * 8;
    int ra2 = la2 >> 2, ka2 = ((la2 & 3) ^ ((ra2 >> 1) & 3)) * 8;
    int rb  = t >> 2,   kb  = ((t & 3) ^ ((rb >> 1) & 3)) * 8;
    const f16* a1 = Ab  + (size_t)ra1 * NF  + ka1;
    const f16* a2 = Ab  + (size_t)ra2 * NF  + ka2;
    const f16* b1 = B1b + (size_t)rb  * TSZ + kb;
    const f16* b2 = B2b + (size_t)rb  * TSZ + kb;

    f32x4 accP[4][4] = {};
    f32x4 accQ[4][4] = {};

    // wave-uniform LDS bases (halfs): hardware adds lane*16B
    int wb = w * 512;
    gl16(a1, As + wb);  gl16(a2, As + 4096 + wb);
    gl16(b1, B1s + wb); gl16(b2, B2s + wb);
    a1 += 32; a2 += 32; b1 += 32; b2 += 32;
    __syncthreads();

    int rA = wr * 64 + (lane & 15);      // A row in [0,256)
    int rB = wc * 64 + (lane & 15);      // B row in [0,128)
    int sl = lane >> 4;

    for (int kt = 0; kt < 16; ++kt) {
        int cur = kt & 1, nxt = cur ^ 1;
        if (kt < 15) {
            gl16(a1, As + nxt * 8192 + wb);  gl16(a2, As + nxt * 8192 + 4096 + wb);
            gl16(b1, B1s + nxt * 4096 + wb); gl16(b2, B2s + nxt * 4096 + wb);
            a1 += 32; a2 += 32; b1 += 32; b2 += 32;
        }
        half8 af[4], bf1[4], bf2[4];
#pragma unroll
        for (int m = 0; m < 4; ++m) {
            int row = rA + m * 16;
            af[m] = *(const half8*)&As[cur * 8192 + row * 32 + ((sl ^ ((row >> 1) & 3)) << 3)];
        }
#pragma unroll
        for (int n = 0; n < 4; ++n) {
            int row = rB + n * 16;
            int o = row * 32 + ((sl ^ ((row >> 1) & 3)) << 3);
            bf1[n] = *(const half8*)&B1s[cur * 4096 + o];
            bf2[n] = *(const half8*)&B2s[cur * 4096 + o];
        }
#pragma unroll
        for (int m = 0; m < 4; ++m)
#pragma unroll
            for (int n = 0; n < 4; ++n) {
                accP[m][n] = __builtin_amdgcn_mfma_f32_16x16x32_f16(af[m], bf1[n], accP[m][n], 0, 0, 0);
                accQ[m][n] = __builtin_amdgcn_mfma_f32_16x16x32_f16(af[m], bf2[n], accQ[m][n], 0, 0, 0);
            }
        __syncthreads();
    }
    // loop ended with __syncthreads: all waves done reading As -> sred may alias it

    // ---- stats epilogue: per-row max/min/sum over this block's 128 cols ----
#define ROW_STATS(ACC, DMX, DMN, DSM)                                          \
    {                                                                          \
        _Pragma("unroll")                                                      \
        for (int m = 0; m < 4; ++m) {                                          \
            _Pragma("unroll")                                                  \
            for (int r = 0; r < 4; ++r) {                                      \
                float mx = -3.4e38f, mn = 3.4e38f, sm = 0.f;                   \
                _Pragma("unroll")                                              \
                for (int n = 0; n < 4; ++n) {                                  \
                    float v = ACC[m][n][r];                                    \
                    mx = fmaxf(mx, v); mn = fminf(mn, v); sm += v;             \
                }                                                              \
                _Pragma("unroll")                                              \
                for (int d = 1; d < 16; d <<= 1) {                             \
                    mx = fmaxf(mx, __shfl_xor(mx, d));                         \
                    mn = fminf(mn, __shfl_xor(mn, d));                         \
                    sm += __shfl_xor(sm, d);                                   \
                }                                                              \
                if ((lane & 15) == 0) {                                        \
                    int row = wr * 64 + m * 16 + (lane >> 4) * 4 + r;          \
                    sred[(row * 2 + wc) * 3 + 0] = mx;                         \
                    sred[(row * 2 + wc) * 3 + 1] = mn;                         \
                    sred[(row * 2 + wc) * 3 + 2] = sm;                         \
                }                                                              \
            }                                                                  \
        }                                                                      \
        __syncthreads();                                                       \
        if (t < 256) {                                                         \
            float mx = fmaxf(sred[(t * 2) * 3 + 0], sred[(t * 2 + 1) * 3 + 0]);\
            float mn = fminf(sred[(t * 2) * 3 + 1], sred[(t * 2 + 1) * 3 + 1]);\
            float sm = sred[(t * 2) * 3 + 2] + sred[(t * 2 + 1) * 3 + 2];      \
            size_t idx = ((size_t)tile * 1024 + mb * 256 + t) * 4 + nb;        \
            DMX[idx] = mx; DMN[idx] = mn; DSM[idx] = sm;                       \
        }                                                                      \
        __syncthreads();                                                       \
    }

    ROW_STATS(accP, pmx, pmn, psm)
    ROW_STATS(accQ, qmx, qmn, qsm)
#undef ROW_STATS

    // ---- store Q (f16) ----
    size_t base = ((size_t)tile * 1024 + mb * 256) * 512 + nb * 128;
#pragma unroll
    for (int m = 0; m < 4; ++m) {
        int row0 = wr * 64 + m * 16 + (lane >> 4) * 4;
#pragma unroll
        for (int n = 0; n < 4; ++n) {
            int col = wc * 64 + n * 16 + (lane & 15);
#pragma unroll
            for (int r = 0; r < 4; ++r)
                Qout[base + (size_t)(row0 + r) * 512 + col] = (f16)accQ[m][n][r];
        }
    }
}

// ---------------- K5: fold partials -> per-(tile,row) alpha/beta ----------------
__global__ void alphabeta(const float* __restrict__ pmx, const float* __restrict__ pmn,
                          const float* __restrict__ psm,
                          const float* __restrict__ qmx, const float* __restrict__ qmn,
                          const float* __restrict__ qsm,
                          const float* __restrict__ pmin1, const float* __restrict__ pmax1,
                          float* __restrict__ alpha, float* __restrict__ beta) {
    int i = blockIdx.x * 256 + threadIdx.x;          // 64 tiles * 1024 rows
    int tile = i >> 10;
    float wmn = 3.4e38f, wmx = -3.4e38f;
#pragma unroll
    for (int u = 0; u < 16; ++u) {
        wmn = fminf(wmn, pmin1[tile * 16 + u]);
        wmx = fmaxf(wmx, pmax1[tile * 16 + u]);
    }
    float s = GRANGE / (wmx - wmn + 1e-12f);
    size_t p = (size_t)i * 4;
    float pmax = fmaxf(fmaxf(pmx[p], pmx[p+1]), fmaxf(pmx[p+2], pmx[p+3]));
    float pmin = fminf(fminf(pmn[p], pmn[p+1]), fminf(pmn[p+2], pmn[p+3]));
    float psum = psm[p] + psm[p+1] + psm[p+2] + psm[p+3];
    float qmax = fmaxf(fmaxf(qmx[p], qmx[p+1]), fmaxf(qmx[p+2], qmx[p+3]));
    float qmin = fminf(fminf(qmn[p], qmn[p+1]), fminf(qmn[p+2], qmn[p+3]));
    float qsum = qsm[p] + qsm[p+1] + qsm[p+2] + qsm[p+3];
    float coeff = (s * (pmax - pmin)) / (s * (qmax - qmin) + 1e-8f);
    float meanP = psum * (1.0f / 512.0f);
    float meanQ = qsum * (1.0f / 512.0f);
    alpha[i] = coeff;
    beta[i]  = meanP - coeff * meanQ;    // out_tile = alpha*Q + beta  (per row)
}

// ---------------- K6: streaming combine ----------------
__global__ __launch_bounds__(256)
void combine(const f16* __restrict__ Q,
             const float* __restrict__ alpha, const float* __restrict__ beta,
             const float* __restrict__ bias, float* __restrict__ out) {
    int bid = blockIdx.x;
    int jt = bid & 7, b = bid >> 3;
    int t = threadIdx.x;
    float o0 = 0.f, o1 = 0.f, bsum = 0.f;
#pragma unroll
    for (int i = 0; i < 8; ++i) {
        int tile = i * 8 + jt;
        int ab = tile * 1024 + b;
        float a = alpha[ab];
        bsum += beta[ab];
        union { uint32_t u; f16 h[2]; } q2;
        q2.u = ((const uint32_t*)(Q + ((size_t)tile * 1024 + b) * 512))[t];
        o0 = fmaf(a, (float)q2.h[0], o0);
        o1 = fmaf(a, (float)q2.h[1], o1);
    }
    float2 bv = ((const float2*)(bias + jt * 512))[t];
    float2 ov; ov.x = o0 + bsum + bv.x; ov.y = o1 + bsum + bv.y;
    ((float2*)(out + (size_t)b * 4096))[jt * 256 + t] = ov;
}

extern "C" void kernel_launch(void* const* d_in, const int* in_sizes, int n_in,
                              void* d_out, int out_size, void* d_ws, size_t ws_size,
                              hipStream_t stream) {
    const float* x    = (const float*)d_in[0];
    const float* wt   = (const float*)d_in[1];
    const float* bias = (const float*)d_in[2];
    float* out = (float*)d_out;
    char* ws = (char*)d_ws;

    float* pmin1 = (float*)ws;                 // 1024 f32 stage-1 partials
    float* pmax1 = (float*)(ws + 4096);        // 1024 f32
    size_t off = 8192;
    f16* xh   = (f16*)(ws + off); off += (size_t)1024 * 4096 * 2;       //   8 MB
    f16* wq_t = (f16*)(ws + off); off += (size_t)4096 * 4096 * 2;       //  32 MB
    f16* h_t  = (f16*)(ws + off); off += (size_t)4096 * 4096 * 2;       //  32 MB
    float* pmx = (float*)(ws + off); off += (size_t)64 * 1024 * 4 * 4;  //   1 MB
    float* pmn = (float*)(ws + off); off += (size_t)64 * 1024 * 4 * 4;
    float* psm = (float*)(ws + off); off += (size_t)64 * 1024 * 4 * 4;
    float* qmx = (float*)(ws + off); off += (size_t)64 * 1024 * 4 * 4;
    float* qmn = (float*)(ws + off); off += (size_t)64 * 1024 * 4 * 4;
    float* qsm = (float*)(ws + off); off += (size_t)64 * 1024 * 4 * 4;
    float* alpha = (float*)(ws + off); off += (size_t)64 * 1024 * 4;    // 256 KB
    float* beta  = (float*)(ws + off); off += (size_t)64 * 1024 * 4;
    f16* Q    = (f16*)(ws + off);                                       //  64 MB

    prep        <<<5120, 256, 0, stream>>>(x, xh, wt, pmin1, pmax1);
    transform_w <<<4096, 256, 0, stream>>>(wt, pmin1, pmax1, wq_t, h_t);
    gemm_fused  <<<1024, 512, 0, stream>>>(xh, wq_t, h_t, Q,
                                           pmx, pmn, psm, qmx, qmn, qsm);
    alphabeta   <<<256,  256, 0, stream>>>(pmx, pmn, psm, qmx, qmn, qsm,
                                           pmin1, pmax1, alpha, beta);
    combine     <<<8192, 256, 0, stream>>>(Q, alpha, beta, bias, out);
}

// Round 7
// 291.761 us; speedup vs baseline: 2.5819x; 2.5819x over previous
//
#include <hip/hip_runtime.h>
#include <hip/hip_fp16.h>
#include <cstdint>

#define DI __device__ __forceinline__

typedef _Float16 f16;
typedef _Float16 half8 __attribute__((ext_vector_type(8)));
typedef float f32x4 __attribute__((ext_vector_type(4)));

constexpr int NF  = 4096;   // features (in = out)
constexpr int TSZ = 512;    // crossbar tile size

// Match JAX f32 weak-typing: f64 python scalars cast to f32 at op time.
constexpr float G_MIN  = (float)(1.0 / 1.0e6);
constexpr float GRANGE = (float)(1.0e-4 - 1.0e-6);            // G_MAX - G_MIN
constexpr float QSTEP  = (float)((1.0e-4 - 1.0e-6) / 15.0);   // (G_MAX-G_MIN)/(2^4-1)

// ---------------- K0: prep = convert_x (blocks 0..4095) ∥ minmax partials ----
__global__ __launch_bounds__(256)
void prep(const float* __restrict__ x, f16* __restrict__ xh,
          const float* __restrict__ w,
          float* __restrict__ pmin, float* __restrict__ pmax) {
    int bid = blockIdx.x;
    int t = threadIdx.x;
    if (bid < 4096) {
        int idx = bid * 256 + t;              // 1M float4
        float4 v = ((const float4*)x)[idx];
        union { f16 h[4]; uint2 u; } o;
        o.h[0] = (f16)v.x; o.h[1] = (f16)v.y; o.h[2] = (f16)v.z; o.h[3] = (f16)v.w;
        ((uint2*)xh)[idx] = o.u;
        return;
    }
    int b2 = bid - 4096;                      // 0..1023
    int tile = b2 >> 4, sub = b2 & 15;
    int it = tile >> 3, jt = tile & 7;
    const float* base = w + (size_t)(it * TSZ + sub * 32) * NF + jt * TSZ;
    float mn = 3.4e38f, mx = -3.4e38f;
#pragma unroll
    for (int i = 0; i < 16; ++i) {
        int idx = i * 256 + t;                // 32 rows x 128 float4
        int r = idx >> 7, c4 = idx & 127;
        float4 v = ((const float4*)(base + (size_t)r * NF))[c4];
        mn = fminf(mn, fminf(fminf(v.x, v.y), fminf(v.z, v.w)));
        mx = fmaxf(mx, fmaxf(fmaxf(v.x, v.y), fmaxf(v.z, v.w)));
    }
    for (int d = 1; d < 64; d <<= 1) {
        mn = fminf(mn, __shfl_xor(mn, d)); mx = fmaxf(mx, __shfl_xor(mx, d));
    }
    __shared__ float smn[4], smx[4];
    int wv = t >> 6;
    if ((t & 63) == 0) { smn[wv] = mn; smx[wv] = mx; }
    __syncthreads();
    if (t == 0) {
        pmin[b2] = fminf(fminf(smn[0], smn[1]), fminf(smn[2], smn[3]));
        pmax[b2] = fmaxf(fmaxf(smx[0], smx[1]), fmaxf(smx[2], smx[3]));
    }
}

// -------- K2: transform w -> wq_f16, H_f16 (transposed: [tile][n][k]) --------
// Quantization arithmetic must match jnp bit-for-bit: unfused f32 mul/add, IEEE
// f32 divide, rintf (ties-to-even). fp contract OFF for this kernel.
__global__ void transform_w(const float* __restrict__ w,
                            const float* __restrict__ pmin, const float* __restrict__ pmax,
                            f16* __restrict__ wq_t, f16* __restrict__ h_t) {
#pragma clang fp contract(off)
    __shared__ f16 lwq[64][72];
    __shared__ f16 lh[64][72];
    int tile = blockIdx.x >> 6; int it = tile >> 3, jt = tile & 7;
    int sub = blockIdx.x & 63; int k0 = (sub >> 3) << 6, n0 = (sub & 7) << 6;
    float wmin = 3.4e38f, wmax = -3.4e38f;
#pragma unroll
    for (int u = 0; u < 16; ++u) {
        wmin = fminf(wmin, pmin[tile * 16 + u]);
        wmax = fmaxf(wmax, pmax[tile * 16 + u]);
    }
    float s = GRANGE / (wmax - wmin + 1e-12f);
    float inv_s = 1.0f / s;
    int t = threadIdx.x, cn = t & 63, r0 = t >> 6;
    for (int rr = 0; rr < 16; ++rr) {
        int rk = rr * 4 + r0;     // local k in [0,64)
        float wv = w[(size_t)(it * TSZ + k0 + rk) * NF + jt * TSZ + n0 + cn];
        float cond  = (wv - wmin) * s + G_MIN;            // unfused, = reference
        float q     = rintf((cond - G_MIN) / QSTEP);      // ties-to-even, IEEE div
        float condq = q * QSTEP + G_MIN;                  // unfused, = reference
        float wqv   = (condq - G_MIN) * inv_s + wmin;     // our own math (any rounding)
        float rw    = 2.0f * ((512.0f - (float)(k0 + rk)) + ((float)(n0 + cn) + 1.0f));
        float ge    = 1.0f / (1.0f / condq + rw);         // IEEE f32 divs, = reference
        lwq[rk][cn] = (f16)wqv;
        lh[rk][cn]  = (f16)(ge * inv_s);
    }
    __syncthreads();
    for (int pp = 0; pp < 8; ++pp) {
        int nl = pp * 8 + (t >> 5);
        int kp = (t & 31) * 2;
        union { f16 h[2]; uint32_t u; } a, b;
        a.h[0] = lwq[kp][nl]; a.h[1] = lwq[kp + 1][nl];
        b.h[0] = lh[kp][nl];  b.h[1] = lh[kp + 1][nl];
        size_t obase = (size_t)tile * TSZ * TSZ + (size_t)(n0 + nl) * TSZ + k0 + kp;
        *(uint32_t*)(wq_t + obase) = a.u;
        *(uint32_t*)(h_t + obase)  = b.u;
    }
}

// ---------------- fused GEMM: 512 thr, 8 waves (4m x 2n), tile M=256 N=128 ----
//   P = x_tile @ wq^T  (stats only)   and   Q = x_tile @ h^T (stats + store)
DI void gl16(const void* g, void* l) {
    auto gp = reinterpret_cast<const uint32_t __attribute__((address_space(1)))*>(
        reinterpret_cast<uintptr_t>(g));
    auto lp = reinterpret_cast<uint32_t __attribute__((address_space(3)))*>(
        reinterpret_cast<uintptr_t>(l));
    __builtin_amdgcn_global_load_lds(gp, lp, 16, 0, 0);
}

// launch_bounds(512, 2): 2 waves/EU -> 256-reg budget. (512,4) = 128-reg budget
// spilled the 128-reg accumulator set to scratch (r6: 1.64 GB writes, 605 us).
__global__ __launch_bounds__(512, 2)
void gemm_fused(const f16* __restrict__ A, const f16* __restrict__ B1,
                const f16* __restrict__ B2, f16* __restrict__ Qout,
                float* __restrict__ pmx, float* __restrict__ pmn, float* __restrict__ psm,
                float* __restrict__ qmx, float* __restrict__ qmn, float* __restrict__ qsm) {
    // 64 KB total: As 2x16KB | B1s 2x8KB | B2s 2x8KB; sred aliases As after loop
    __shared__ __align__(16) char smem[65536];
    f16* As  = (f16*)smem;               // [2][256r * 32k]
    f16* B1s = (f16*)(smem + 32768);     // [2][128r * 32k]
    f16* B2s = (f16*)(smem + 49152);     // [2][128r * 32k]
    float* sred = (float*)smem;          // [256][2][3] (aliases As; used after loop)

    int bx = blockIdx.x;                 // 64 tiles * 4 mb * 4 nb = 1024 blocks
    int tile = bx >> 4, mb = (bx >> 2) & 3, nb = bx & 3;
    int it = tile >> 3;
    int t = threadIdx.x, lane = t & 63, w = t >> 6;   // 8 waves
    int wr = w >> 1, wc = w & 1;                      // 4 m-waves x 2 n-waves

    const f16* Ab  = A  + (size_t)(mb * 256) * NF + it * TSZ;
    const f16* B1b = B1 + ((size_t)tile * TSZ + nb * 128) * TSZ;
    const f16* B2b = B2 + ((size_t)tile * TSZ + nb * 128) * TSZ;

    // staging: A 1024 chunks (t, t+512), B1/B2 512 chunks (t) per K-step.
    // chunk l -> LDS halfs [8l, 8l+8); source k pre-swizzled: (slot^((row>>1)&3))*8
    int la1 = t, la2 = t + 512;
    int ra1 = la1 >> 2, ka1 = ((la1 & 3) ^ ((ra1 >> 1) & 3)) * 8;
    int ra2 = la2 >> 2, ka2 = ((la2 & 3) ^ ((ra2 >> 1) & 3)) * 8;
    int rb  = t >> 2,   kb  = ((t & 3) ^ ((rb >> 1) & 3)) * 8;
    const f16* a1 = Ab  + (size_t)ra1 * NF  + ka1;
    const f16* a2 = Ab  + (size_t)ra2 * NF  + ka2;
    const f16* b1 = B1b + (size_t)rb  * TSZ + kb;
    const f16* b2 = B2b + (size_t)rb  * TSZ + kb;

    f32x4 accP[4][4] = {};
    f32x4 accQ[4][4] = {};

    // wave-uniform LDS bases (halfs): hardware adds lane*16B
    int wb = w * 512;
    gl16(a1, As + wb);  gl16(a2, As + 4096 + wb);
    gl16(b1, B1s + wb); gl16(b2, B2s + wb);
    a1 += 32; a2 += 32; b1 += 32; b2 += 32;
    __syncthreads();

    int rA = wr * 64 + (lane & 15);      // A row in [0,256)
    int rB = wc * 64 + (lane & 15);      // B row in [0,128)
    int sl = lane >> 4;

    for (int kt = 0; kt < 16; ++kt) {
        int cur = kt & 1, nxt = cur ^ 1;
        if (kt < 15) {
            gl16(a1, As + nxt * 8192 + wb);  gl16(a2, As + nxt * 8192 + 4096 + wb);
            gl16(b1, B1s + nxt * 4096 + wb); gl16(b2, B2s + nxt * 4096 + wb);
            a1 += 32; a2 += 32; b1 += 32; b2 += 32;
        }
        half8 af[4], bf1[4], bf2[4];
#pragma unroll
        for (int m = 0; m < 4; ++m) {
            int row = rA + m * 16;
            af[m] = *(const half8*)&As[cur * 8192 + row * 32 + ((sl ^ ((row >> 1) & 3)) << 3)];
        }
#pragma unroll
        for (int n = 0; n < 4; ++n) {
            int row = rB + n * 16;
            int o = row * 32 + ((sl ^ ((row >> 1) & 3)) << 3);
            bf1[n] = *(const half8*)&B1s[cur * 4096 + o];
            bf2[n] = *(const half8*)&B2s[cur * 4096 + o];
        }
#pragma unroll
        for (int m = 0; m < 4; ++m)
#pragma unroll
            for (int n = 0; n < 4; ++n) {
                accP[m][n] = __builtin_amdgcn_mfma_f32_16x16x32_f16(af[m], bf1[n], accP[m][n], 0, 0, 0);
                accQ[m][n] = __builtin_amdgcn_mfma_f32_16x16x32_f16(af[m], bf2[n], accQ[m][n], 0, 0, 0);
            }
        __syncthreads();
    }
    // loop ended with __syncthreads: all waves done reading As -> sred may alias it

    // ---- stats epilogue: per-row max/min/sum over this block's 128 cols ----
#define ROW_STATS(ACC, DMX, DMN, DSM)                                          \
    {                                                                          \
        _Pragma("unroll")                                                      \
        for (int m = 0; m < 4; ++m) {                                          \
            _Pragma("unroll")                                                  \
            for (int r = 0; r < 4; ++r) {                                      \
                float mx = -3.4e38f, mn = 3.4e38f, sm = 0.f;                   \
                _Pragma("unroll")                                              \
                for (int n = 0; n < 4; ++n) {                                  \
                    float v = ACC[m][n][r];                                    \
                    mx = fmaxf(mx, v); mn = fminf(mn, v); sm += v;             \
                }                                                              \
                _Pragma("unroll")                                              \
                for (int d = 1; d < 16; d <<= 1) {                             \
                    mx = fmaxf(mx, __shfl_xor(mx, d));                         \
                    mn = fminf(mn, __shfl_xor(mn, d));                         \
                    sm += __shfl_xor(sm, d);                                   \
                }                                                              \
                if ((lane & 15) == 0) {                                        \
                    int row = wr * 64 + m * 16 + (lane >> 4) * 4 + r;          \
                    sred[(row * 2 + wc) * 3 + 0] = mx;                         \
                    sred[(row * 2 + wc) * 3 + 1] = mn;                         \
                    sred[(row * 2 + wc) * 3 + 2] = sm;                         \
                }                                                              \
            }                                                                  \
        }                                                                      \
        __syncthreads();                                                       \
        if (t < 256) {                                                         \
            float mx = fmaxf(sred[(t * 2) * 3 + 0], sred[(t * 2 + 1) * 3 + 0]);\
            float mn = fminf(sred[(t * 2) * 3 + 1], sred[(t * 2 + 1) * 3 + 1]);\
            float sm = sred[(t * 2) * 3 + 2] + sred[(t * 2 + 1) * 3 + 2];      \
            size_t idx = ((size_t)tile * 1024 + mb * 256 + t) * 4 + nb;        \
            DMX[idx] = mx; DMN[idx] = mn; DSM[idx] = sm;                       \
        }                                                                      \
        __syncthreads();                                                       \
    }

    ROW_STATS(accP, pmx, pmn, psm)
    ROW_STATS(accQ, qmx, qmn, qsm)
#undef ROW_STATS

    // ---- store Q (f16) ----
    size_t base = ((size_t)tile * 1024 + mb * 256) * 512 + nb * 128;
#pragma unroll
    for (int m = 0; m < 4; ++m) {
        int row0 = wr * 64 + m * 16 + (lane >> 4) * 4;
#pragma unroll
        for (int n = 0; n < 4; ++n) {
            int col = wc * 64 + n * 16 + (lane & 15);
#pragma unroll
            for (int r = 0; r < 4; ++r)
                Qout[base + (size_t)(row0 + r) * 512 + col] = (f16)accQ[m][n][r];
        }
    }
}

// ---------------- K5: fold partials -> per-(tile,row) alpha/beta ----------------
__global__ void alphabeta(const float* __restrict__ pmx, const float* __restrict__ pmn,
                          const float* __restrict__ psm,
                          const float* __restrict__ qmx, const float* __restrict__ qmn,
                          const float* __restrict__ qsm,
                          const float* __restrict__ pmin1, const float* __restrict__ pmax1,
                          float* __restrict__ alpha, float* __restrict__ beta) {
    int i = blockIdx.x * 256 + threadIdx.x;          // 64 tiles * 1024 rows
    int tile = i >> 10;
    float wmn = 3.4e38f, wmx = -3.4e38f;
#pragma unroll
    for (int u = 0; u < 16; ++u) {
        wmn = fminf(wmn, pmin1[tile * 16 + u]);
        wmx = fmaxf(wmx, pmax1[tile * 16 + u]);
    }
    float s = GRANGE / (wmx - wmn + 1e-12f);
    size_t p = (size_t)i * 4;
    float pmax = fmaxf(fmaxf(pmx[p], pmx[p+1]), fmaxf(pmx[p+2], pmx[p+3]));
    float pmin = fminf(fminf(pmn[p], pmn[p+1]), fminf(pmn[p+2], pmn[p+3]));
    float psum = psm[p] + psm[p+1] + psm[p+2] + psm[p+3];
    float qmax = fmaxf(fmaxf(qmx[p], qmx[p+1]), fmaxf(qmx[p+2], qmx[p+3]));
    float qmin = fminf(fminf(qmn[p], qmn[p+1]), fminf(qmn[p+2], qmn[p+3]));
    float qsum = qsm[p] + qsm[p+1] + qsm[p+2] + qsm[p+3];
    float coeff = (s * (pmax - pmin)) / (s * (qmax - qmin) + 1e-8f);
    float meanP = psum * (1.0f / 512.0f);
    float meanQ = qsum * (1.0f / 512.0f);
    alpha[i] = coeff;
    beta[i]  = meanP - coeff * meanQ;    // out_tile = alpha*Q + beta  (per row)
}

// ---------------- K6: streaming combine ----------------
__global__ __launch_bounds__(256)
void combine(const f16* __restrict__ Q,
             const float* __restrict__ alpha, const float* __restrict__ beta,
             const float* __restrict__ bias, float* __restrict__ out) {
    int bid = blockIdx.x;
    int jt = bid & 7, b = bid >> 3;
    int t = threadIdx.x;
    float o0 = 0.f, o1 = 0.f, bsum = 0.f;
#pragma unroll
    for (int i = 0; i < 8; ++i) {
        int tile = i * 8 + jt;
        int ab = tile * 1024 + b;
        float a = alpha[ab];
        bsum += beta[ab];
        union { uint32_t u; f16 h[2]; } q2;
        q2.u = ((const uint32_t*)(Q + ((size_t)tile * 1024 + b) * 512))[t];
        o0 = fmaf(a, (float)q2.h[0], o0);
        o1 = fmaf(a, (float)q2.h[1], o1);
    }
    float2 bv = ((const float2*)(bias + jt * 512))[t];
    float2 ov; ov.x = o0 + bsum + bv.x; ov.y = o1 + bsum + bv.y;
    ((float2*)(out + (size_t)b * 4096))[jt * 256 + t] = ov;
}

extern "C" void kernel_launch(void* const* d_in, const int* in_sizes, int n_in,
                              void* d_out, int out_size, void* d_ws, size_t ws_size,
                              hipStream_t stream) {
    const float* x    = (const float*)d_in[0];
    const float* wt   = (const float*)d_in[1];
    const float* bias = (const float*)d_in[2];
    float* out = (float*)d_out;
    char* ws = (char*)d_ws;

    float* pmin1 = (float*)ws;                 // 1024 f32 stage-1 partials
    float* pmax1 = (float*)(ws + 4096);        // 1024 f32
    size_t off = 8192;
    f16* xh   = (f16*)(ws + off); off += (size_t)1024 * 4096 * 2;       //   8 MB
    f16* wq_t = (f16*)(ws + off); off += (size_t)4096 * 4096 * 2;       //  32 MB
    f16* h_t  = (f16*)(ws + off); off += (size_t)4096 * 4096 * 2;       //  32 MB
    float* pmx = (float*)(ws + off); off += (size_t)64 * 1024 * 4 * 4;  //   1 MB
    float* pmn = (float*)(ws + off); off += (size_t)64 * 1024 * 4 * 4;
    float* psm = (float*)(ws + off); off += (size_t)64 * 1024 * 4 * 4;
    float* qmx = (float*)(ws + off); off += (size_t)64 * 1024 * 4 * 4;
    float* qmn = (float*)(ws + off); off += (size_t)64 * 1024 * 4 * 4;
    float* qsm = (float*)(ws + off); off += (size_t)64 * 1024 * 4 * 4;
    float* alpha = (float*)(ws + off); off += (size_t)64 * 1024 * 4;    // 256 KB
    float* beta  = (float*)(ws + off); off += (size_t)64 * 1024 * 4;
    f16* Q    = (f16*)(ws + off);                                       //  64 MB

    prep        <<<5120, 256, 0, stream>>>(x, xh, wt, pmin1, pmax1);
    transform_w <<<4096, 256, 0, stream>>>(wt, pmin1, pmax1, wq_t, h_t);
    gemm_fused  <<<1024, 512, 0, stream>>>(xh, wq_t, h_t, Q,
                                           pmx, pmn, psm, qmx, qmn, qsm);
    alphabeta   <<<256,  256, 0, stream>>>(pmx, pmn, psm, qmx, qmn, qsm,
                                           pmin1, pmax1, alpha, beta);
    combine     <<<8192, 256, 0, stream>>>(Q, alpha, beta, bias, out);
}

// Round 8
// 285.281 us; speedup vs baseline: 2.6405x; 1.0227x over previous
//
#include <hip/hip_runtime.h>
#include <hip/hip_fp16.h>
#include <cstdint>

#define DI __device__ __forceinline__

typedef _Float16 f16;
typedef _Float16 half8 __attribute__((ext_vector_type(8)));
typedef float f32x4 __attribute__((ext_vector_type(4)));

constexpr int NF  = 4096;   // features (in = out)
constexpr int TSZ = 512;    // crossbar tile size

// Match JAX f32 weak-typing: f64 python scalars cast to f32 at op time.
constexpr float G_MIN  = (float)(1.0 / 1.0e6);
constexpr float GRANGE = (float)(1.0e-4 - 1.0e-6);            // G_MAX - G_MIN
constexpr float QSTEP  = (float)((1.0e-4 - 1.0e-6) / 15.0);   // (G_MAX-G_MIN)/(2^4-1)

// ---------------- K0: prep = convert_x (blocks 0..4095) ∥ minmax partials ----
__global__ __launch_bounds__(256)
void prep(const float* __restrict__ x, f16* __restrict__ xh,
          const float* __restrict__ w,
          float* __restrict__ pmin, float* __restrict__ pmax) {
    int bid = blockIdx.x;
    int t = threadIdx.x;
    if (bid < 4096) {
        int idx = bid * 256 + t;              // 1M float4
        float4 v = ((const float4*)x)[idx];
        union { f16 h[4]; uint2 u; } o;
        o.h[0] = (f16)v.x; o.h[1] = (f16)v.y; o.h[2] = (f16)v.z; o.h[3] = (f16)v.w;
        ((uint2*)xh)[idx] = o.u;
        return;
    }
    int b2 = bid - 4096;                      // 0..1023
    int tile = b2 >> 4, sub = b2 & 15;
    int it = tile >> 3, jt = tile & 7;
    const float* base = w + (size_t)(it * TSZ + sub * 32) * NF + jt * TSZ;
    float mn = 3.4e38f, mx = -3.4e38f;
#pragma unroll
    for (int i = 0; i < 16; ++i) {
        int idx = i * 256 + t;                // 32 rows x 128 float4
        int r = idx >> 7, c4 = idx & 127;
        float4 v = ((const float4*)(base + (size_t)r * NF))[c4];
        mn = fminf(mn, fminf(fminf(v.x, v.y), fminf(v.z, v.w)));
        mx = fmaxf(mx, fmaxf(fmaxf(v.x, v.y), fmaxf(v.z, v.w)));
    }
    for (int d = 1; d < 64; d <<= 1) {
        mn = fminf(mn, __shfl_xor(mn, d)); mx = fmaxf(mx, __shfl_xor(mx, d));
    }
    __shared__ float smn[4], smx[4];
    int wv = t >> 6;
    if ((t & 63) == 0) { smn[wv] = mn; smx[wv] = mx; }
    __syncthreads();
    if (t == 0) {
        pmin[b2] = fminf(fminf(smn[0], smn[1]), fminf(smn[2], smn[3]));
        pmax[b2] = fmaxf(fmaxf(smx[0], smx[1]), fmaxf(smx[2], smx[3]));
    }
}

// -------- K2: transform w -> wq_f16, H_f16 (transposed: [tile][n][k]) --------
// Quantization arithmetic must match jnp bit-for-bit: unfused f32 mul/add, IEEE
// f32 divide, rintf (ties-to-even). fp contract OFF for this kernel.
__global__ void transform_w(const float* __restrict__ w,
                            const float* __restrict__ pmin, const float* __restrict__ pmax,
                            f16* __restrict__ wq_t, f16* __restrict__ h_t) {
#pragma clang fp contract(off)
    __shared__ f16 lwq[64][72];
    __shared__ f16 lh[64][72];
    int tile = blockIdx.x >> 6; int it = tile >> 3, jt = tile & 7;
    int sub = blockIdx.x & 63; int k0 = (sub >> 3) << 6, n0 = (sub & 7) << 6;
    float wmin = 3.4e38f, wmax = -3.4e38f;
#pragma unroll
    for (int u = 0; u < 16; ++u) {
        wmin = fminf(wmin, pmin[tile * 16 + u]);
        wmax = fmaxf(wmax, pmax[tile * 16 + u]);
    }
    float s = GRANGE / (wmax - wmin + 1e-12f);
    float inv_s = 1.0f / s;
    int t = threadIdx.x, cn = t & 63, r0 = t >> 6;
    for (int rr = 0; rr < 16; ++rr) {
        int rk = rr * 4 + r0;     // local k in [0,64)
        float wv = w[(size_t)(it * TSZ + k0 + rk) * NF + jt * TSZ + n0 + cn];
        float cond  = (wv - wmin) * s + G_MIN;            // unfused, = reference
        float q     = rintf((cond - G_MIN) / QSTEP);      // ties-to-even, IEEE div
        float condq = q * QSTEP + G_MIN;                  // unfused, = reference
        float wqv   = (condq - G_MIN) * inv_s + wmin;     // our own math (any rounding)
        float rw    = 2.0f * ((512.0f - (float)(k0 + rk)) + ((float)(n0 + cn) + 1.0f));
        float ge    = 1.0f / (1.0f / condq + rw);         // IEEE f32 divs, = reference
        lwq[rk][cn] = (f16)wqv;
        lh[rk][cn]  = (f16)(ge * inv_s);
    }
    __syncthreads();
    for (int pp = 0; pp < 8; ++pp) {
        int nl = pp * 8 + (t >> 5);
        int kp = (t & 31) * 2;
        union { f16 h[2]; uint32_t u; } a, b;
        a.h[0] = lwq[kp][nl]; a.h[1] = lwq[kp + 1][nl];
        b.h[0] = lh[kp][nl];  b.h[1] = lh[kp + 1][nl];
        size_t obase = (size_t)tile * TSZ * TSZ + (size_t)(n0 + nl) * TSZ + k0 + kp;
        *(uint32_t*)(wq_t + obase) = a.u;
        *(uint32_t*)(h_t + obase)  = b.u;
    }
}

// ---------------- fused GEMM: 512 thr, 8 waves (4m x 2n), tile M=256 N=128 ----
//   P = x_tile @ wq^T  (stats only)   and   Q = x_tile @ h^T (stats + store)
DI void gl16(const void* g, void* l) {
    auto gp = reinterpret_cast<const uint32_t __attribute__((address_space(1)))*>(
        reinterpret_cast<uintptr_t>(g));
    auto lp = reinterpret_cast<uint32_t __attribute__((address_space(3)))*>(
        reinterpret_cast<uintptr_t>(l));
    __builtin_amdgcn_global_load_lds(gp, lp, 16, 0, 0);
}

// launch_bounds(512, 2): 2 waves/EU -> 256-reg budget ((512,4) spilled, r6).
// K-loop uses counted vmcnt (T4): never drain to 0 in the main loop.
//   barrier#1 (top): s_waitcnt vmcnt(4) + s_barrier -> cur buffer ready, the 4
//                    just-issued nxt loads stay in flight under the MFMA phase.
//   barrier#2 (end): plain s_barrier -> all reads of cur retired (lgkmcnt
//                    enforced before MFMA use), so kt+1 may overwrite cur.
__global__ __launch_bounds__(512, 2)
void gemm_fused(const f16* __restrict__ A, const f16* __restrict__ B1,
                const f16* __restrict__ B2, f16* __restrict__ Qout,
                float* __restrict__ pmx, float* __restrict__ pmn, float* __restrict__ psm,
                float* __restrict__ qmx, float* __restrict__ qmn, float* __restrict__ qsm) {
    // 64 KB total: As 2x16KB | B1s 2x8KB | B2s 2x8KB; sred aliases As after loop
    __shared__ __align__(16) char smem[65536];
    f16* As  = (f16*)smem;               // [2][256r * 32k]
    f16* B1s = (f16*)(smem + 32768);     // [2][128r * 32k]
    f16* B2s = (f16*)(smem + 49152);     // [2][128r * 32k]
    float* sred = (float*)smem;          // [256][2][3] (aliases As; used after loop)

    int bx = blockIdx.x;                 // 64 tiles * 4 mb * 4 nb = 1024 blocks
    int tile = bx >> 4, mb = (bx >> 2) & 3, nb = bx & 3;
    int it = tile >> 3;
    int t = threadIdx.x, lane = t & 63, w = t >> 6;   // 8 waves
    int wr = w >> 1, wc = w & 1;                      // 4 m-waves x 2 n-waves

    const f16* Ab  = A  + (size_t)(mb * 256) * NF + it * TSZ;
    const f16* B1b = B1 + ((size_t)tile * TSZ + nb * 128) * TSZ;
    const f16* B2b = B2 + ((size_t)tile * TSZ + nb * 128) * TSZ;

    // staging: A 1024 chunks (t, t+512), B1/B2 512 chunks (t) per K-step.
    // chunk l -> LDS halfs [8l, 8l+8); source k pre-swizzled: (slot^((row>>1)&3))*8
    int la1 = t, la2 = t + 512;
    int ra1 = la1 >> 2, ka1 = ((la1 & 3) ^ ((ra1 >> 1) & 3)) * 8;
    int ra2 = la2 >> 2, ka2 = ((la2 & 3) ^ ((ra2 >> 1) & 3)) * 8;
    int rb  = t >> 2,   kb  = ((t & 3) ^ ((rb >> 1) & 3)) * 8;
    const f16* a1 = Ab  + (size_t)ra1 * NF  + ka1;
    const f16* a2 = Ab  + (size_t)ra2 * NF  + ka2;
    const f16* b1 = B1b + (size_t)rb  * TSZ + kb;
    const f16* b2 = B2b + (size_t)rb  * TSZ + kb;

    f32x4 accP[4][4] = {};
    f32x4 accQ[4][4] = {};

    // wave-uniform LDS bases (halfs): hardware adds lane*16B
    int wb = w * 512;
    gl16(a1, As + wb);  gl16(a2, As + 4096 + wb);
    gl16(b1, B1s + wb); gl16(b2, B2s + wb);
    a1 += 32; a2 += 32; b1 += 32; b2 += 32;
    // no full __syncthreads here: loop's barrier#1 (vmcnt+barrier) covers it

    int rA = wr * 64 + (lane & 15);      // A row in [0,256)
    int rB = wc * 64 + (lane & 15);      // B row in [0,128)
    int sl = lane >> 4;

    for (int kt = 0; kt < 16; ++kt) {
        int cur = kt & 1, nxt = cur ^ 1;
        if (kt < 15) {
            gl16(a1, As + nxt * 8192 + wb);  gl16(a2, As + nxt * 8192 + 4096 + wb);
            gl16(b1, B1s + nxt * 4096 + wb); gl16(b2, B2s + nxt * 4096 + wb);
            a1 += 32; a2 += 32; b1 += 32; b2 += 32;
            asm volatile("s_waitcnt vmcnt(4)" ::: "memory");   // cur done; nxt in flight
        } else {
            asm volatile("s_waitcnt vmcnt(0)" ::: "memory");   // last tile: full drain
        }
        __builtin_amdgcn_s_barrier();

        half8 af[4], bf1[4], bf2[4];
#pragma unroll
        for (int m = 0; m < 4; ++m) {
            int row = rA + m * 16;
            af[m] = *(const half8*)&As[cur * 8192 + row * 32 + ((sl ^ ((row >> 1) & 3)) << 3)];
        }
#pragma unroll
        for (int n = 0; n < 4; ++n) {
            int row = rB + n * 16;
            int o = row * 32 + ((sl ^ ((row >> 1) & 3)) << 3);
            bf1[n] = *(const half8*)&B1s[cur * 4096 + o];
            bf2[n] = *(const half8*)&B2s[cur * 4096 + o];
        }
#pragma unroll
        for (int m = 0; m < 4; ++m)
#pragma unroll
            for (int n = 0; n < 4; ++n) {
                accP[m][n] = __builtin_amdgcn_mfma_f32_16x16x32_f16(af[m], bf1[n], accP[m][n], 0, 0, 0);
                accQ[m][n] = __builtin_amdgcn_mfma_f32_16x16x32_f16(af[m], bf2[n], accQ[m][n], 0, 0, 0);
            }
        __builtin_amdgcn_s_barrier();     // reads of cur retired -> kt+1 may overwrite
    }
    // kt=15 used vmcnt(0); barrier#2 passed -> safe to alias sred onto As

    // ---- stats epilogue: per-row max/min/sum over this block's 128 cols ----
#define ROW_STATS(ACC, DMX, DMN, DSM)                                          \
    {                                                                          \
        _Pragma("unroll")                                                      \
        for (int m = 0; m < 4; ++m) {                                          \
            _Pragma("unroll")                                                  \
            for (int r = 0; r < 4; ++r) {                                      \
                float mx = -3.4e38f, mn = 3.4e38f, sm = 0.f;                   \
                _Pragma("unroll")                                              \
                for (int n = 0; n < 4; ++n) {                                  \
                    float v = ACC[m][n][r];                                    \
                    mx = fmaxf(mx, v); mn = fminf(mn, v); sm += v;             \
                }                                                              \
                _Pragma("unroll")                                              \
                for (int d = 1; d < 16; d <<= 1) {                             \
                    mx = fmaxf(mx, __shfl_xor(mx, d));                         \
                    mn = fminf(mn, __shfl_xor(mn, d));                         \
                    sm += __shfl_xor(sm, d);                                   \
                }                                                              \
                if ((lane & 15) == 0) {                                        \
                    int row = wr * 64 + m * 16 + (lane >> 4) * 4 + r;          \
                    sred[(row * 2 + wc) * 3 + 0] = mx;                         \
                    sred[(row * 2 + wc) * 3 + 1] = mn;                         \
                    sred[(row * 2 + wc) * 3 + 2] = sm;                         \
                }                                                              \
            }                                                                  \
        }                                                                      \
        __syncthreads();                                                       \
        if (t < 256) {                                                         \
            float mx = fmaxf(sred[(t * 2) * 3 + 0], sred[(t * 2 + 1) * 3 + 0]);\
            float mn = fminf(sred[(t * 2) * 3 + 1], sred[(t * 2 + 1) * 3 + 1]);\
            float sm = sred[(t * 2) * 3 + 2] + sred[(t * 2 + 1) * 3 + 2];      \
            size_t idx = ((size_t)tile * 1024 + mb * 256 + t) * 4 + nb;        \
            DMX[idx] = mx; DMN[idx] = mn; DSM[idx] = sm;                       \
        }                                                                      \
        __syncthreads();                                                       \
    }

    ROW_STATS(accP, pmx, pmn, psm)
    ROW_STATS(accQ, qmx, qmn, qsm)
#undef ROW_STATS

    // ---- store Q (f16) ----
    size_t base = ((size_t)tile * 1024 + mb * 256) * 512 + nb * 128;
#pragma unroll
    for (int m = 0; m < 4; ++m) {
        int row0 = wr * 64 + m * 16 + (lane >> 4) * 4;
#pragma unroll
        for (int n = 0; n < 4; ++n) {
            int col = wc * 64 + n * 16 + (lane & 15);
#pragma unroll
            for (int r = 0; r < 4; ++r)
                Qout[base + (size_t)(row0 + r) * 512 + col] = (f16)accQ[m][n][r];
        }
    }
}

// ---------------- K5: fold partials -> per-(tile,row) alpha/beta ----------------
__global__ void alphabeta(const float* __restrict__ pmx, const float* __restrict__ pmn,
                          const float* __restrict__ psm,
                          const float* __restrict__ qmx, const float* __restrict__ qmn,
                          const float* __restrict__ qsm,
                          const float* __restrict__ pmin1, const float* __restrict__ pmax1,
                          float* __restrict__ alpha, float* __restrict__ beta) {
    int i = blockIdx.x * 256 + threadIdx.x;          // 64 tiles * 1024 rows
    int tile = i >> 10;
    float wmn = 3.4e38f, wmx = -3.4e38f;
#pragma unroll
    for (int u = 0; u < 16; ++u) {
        wmn = fminf(wmn, pmin1[tile * 16 + u]);
        wmx = fmaxf(wmx, pmax1[tile * 16 + u]);
    }
    float s = GRANGE / (wmx - wmn + 1e-12f);
    size_t p = (size_t)i * 4;
    float pmax = fmaxf(fmaxf(pmx[p], pmx[p+1]), fmaxf(pmx[p+2], pmx[p+3]));
    float pmin = fminf(fminf(pmn[p], pmn[p+1]), fminf(pmn[p+2], pmn[p+3]));
    float psum = psm[p] + psm[p+1] + psm[p+2] + psm[p+3];
    float qmax = fmaxf(fmaxf(qmx[p], qmx[p+1]), fmaxf(qmx[p+2], qmx[p+3]));
    float qmin = fminf(fminf(qmn[p], qmn[p+1]), fminf(qmn[p+2], qmn[p+3]));
    float qsum = qsm[p] + qsm[p+1] + qsm[p+2] + qsm[p+3];
    float coeff = (s * (pmax - pmin)) / (s * (qmax - qmin) + 1e-8f);
    float meanP = psum * (1.0f / 512.0f);
    float meanQ = qsum * (1.0f / 512.0f);
    alpha[i] = coeff;
    beta[i]  = meanP - coeff * meanQ;    // out_tile = alpha*Q + beta  (per row)
}

// ---------------- K6: streaming combine ----------------
__global__ __launch_bounds__(256)
void combine(const f16* __restrict__ Q,
             const float* __restrict__ alpha, const float* __restrict__ beta,
             const float* __restrict__ bias, float* __restrict__ out) {
    int bid = blockIdx.x;
    int jt = bid & 7, b = bid >> 3;
    int t = threadIdx.x;
    float o0 = 0.f, o1 = 0.f, bsum = 0.f;
#pragma unroll
    for (int i = 0; i < 8; ++i) {
        int tile = i * 8 + jt;
        int ab = tile * 1024 + b;
        float a = alpha[ab];
        bsum += beta[ab];
        union { uint32_t u; f16 h[2]; } q2;
        q2.u = ((const uint32_t*)(Q + ((size_t)tile * 1024 + b) * 512))[t];
        o0 = fmaf(a, (float)q2.h[0], o0);
        o1 = fmaf(a, (float)q2.h[1], o1);
    }
    float2 bv = ((const float2*)(bias + jt * 512))[t];
    float2 ov; ov.x = o0 + bsum + bv.x; ov.y = o1 + bsum + bv.y;
    ((float2*)(out + (size_t)b * 4096))[jt * 256 + t] = ov;
}

extern "C" void kernel_launch(void* const* d_in, const int* in_sizes, int n_in,
                              void* d_out, int out_size, void* d_ws, size_t ws_size,
                              hipStream_t stream) {
    const float* x    = (const float*)d_in[0];
    const float* wt   = (const float*)d_in[1];
    const float* bias = (const float*)d_in[2];
    float* out = (float*)d_out;
    char* ws = (char*)d_ws;

    float* pmin1 = (float*)ws;                 // 1024 f32 stage-1 partials
    float* pmax1 = (float*)(ws + 4096);        // 1024 f32
    size_t off = 8192;
    f16* xh   = (f16*)(ws + off); off += (size_t)1024 * 4096 * 2;       //   8 MB
    f16* wq_t = (f16*)(ws + off); off += (size_t)4096 * 4096 * 2;       //  32 MB
    f16* h_t  = (f16*)(ws + off); off += (size_t)4096 * 4096 * 2;       //  32 MB
    float* pmx = (float*)(ws + off); off += (size_t)64 * 1024 * 4 * 4;  //   1 MB
    float* pmn = (float*)(ws + off); off += (size_t)64 * 1024 * 4 * 4;
    float* psm = (float*)(ws + off); off += (size_t)64 * 1024 * 4 * 4;
    float* qmx = (float*)(ws + off); off += (size_t)64 * 1024 * 4 * 4;
    float* qmn = (float*)(ws + off); off += (size_t)64 * 1024 * 4 * 4;
    float* qsm = (float*)(ws + off); off += (size_t)64 * 1024 * 4 * 4;
    float* alpha = (float*)(ws + off); off += (size_t)64 * 1024 * 4;    // 256 KB
    float* beta  = (float*)(ws + off); off += (size_t)64 * 1024 * 4;
    f16* Q    = (f16*)(ws + off);                                       //  64 MB

    prep        <<<5120, 256, 0, stream>>>(x, xh, wt, pmin1, pmax1);
    transform_w <<<4096, 256, 0, stream>>>(wt, pmin1, pmax1, wq_t, h_t);
    gemm_fused  <<<1024, 512, 0, stream>>>(xh, wq_t, h_t, Q,
                                           pmx, pmn, psm, qmx, qmn, qsm);
    alphabeta   <<<256,  256, 0, stream>>>(pmx, pmn, psm, qmx, qmn, qsm,
                                           pmin1, pmax1, alpha, beta);
    combine     <<<8192, 256, 0, stream>>>(Q, alpha, beta, bias, out);
}